// Round 6
// baseline (407.444 us; speedup 1.0000x reference)
//
#include <hip/hip_runtime.h>

#define N_BINS 30
#define BLOCK 256
#define GRID 2048

// ECE = sum_b | sum_{i in bin b} (conf_i - acc_i) | / N  (counts cancel).
// Accumulator: per-thread PRIVATE slot in LDS, s_acc[bin*256 + tid].
//  - dynamic LDS indexing is native (ds ops take VGPR addr) -> nothing for the
//    compiler to demote (R4: float[30] -> scratch; R5: 30 named floats -> scratch).
//  - no atomics, no barriers in the main loop; bank = tid&31 -> 2-way = free.
// Workspace: 30 x i64 fixed-point (2^20) sums + 1 u32 done counter (memset 0).

__global__ __launch_bounds__(BLOCK) void ece_hist(
        const float* __restrict__ sm,
        const int*   __restrict__ labels,
        int n,
        unsigned long long* __restrict__ g_sum,
        unsigned int* __restrict__ done,
        float* __restrict__ out) {
    __shared__ float s_acc[N_BINS * BLOCK];   // 30 KB: [bin][thread]
    __shared__ unsigned int s_last;

    const int tid = threadIdx.x;

    #pragma unroll
    for (int b = 0; b < N_BINS; ++b) s_acc[b * BLOCK + tid] = 0.0f;
    // no barrier: each thread touches only its own column until the flush

    const int stride = gridDim.x * BLOCK;
    for (int r = blockIdx.x * BLOCK + tid; r < n; r += stride) {
        const float* row = sm + (long long)r * 10;
        float2 q0 = *reinterpret_cast<const float2*>(row + 0);
        float2 q1 = *reinterpret_cast<const float2*>(row + 2);
        float2 q2 = *reinterpret_cast<const float2*>(row + 4);
        float2 q3 = *reinterpret_cast<const float2*>(row + 6);
        float2 q4 = *reinterpret_cast<const float2*>(row + 8);
        int lbl = labels[r];

        // first-occurrence argmax (strict >)
        float conf = q0.x; int pred = 0;
        if (q0.y > conf) { conf = q0.y; pred = 1; }
        if (q1.x > conf) { conf = q1.x; pred = 2; }
        if (q1.y > conf) { conf = q1.y; pred = 3; }
        if (q2.x > conf) { conf = q2.x; pred = 4; }
        if (q2.y > conf) { conf = q2.y; pred = 5; }
        if (q3.x > conf) { conf = q3.x; pred = 6; }
        if (q3.y > conf) { conf = q3.y; pred = 7; }
        if (q4.x > conf) { conf = q4.x; pred = 8; }
        if (q4.y > conf) { conf = q4.y; pred = 9; }

        int bin = min(max((int)ceilf(conf * 30.0f) - 1, 0), N_BINS - 1);
        float d = conf - ((pred == lbl) ? 1.0f : 0.0f);

        s_acc[bin * BLOCK + tid] += d;        // private slot: ds_read+add+ds_write
    }
    __syncthreads();

    // ---- block flush: wave w reduces bins 8w..8w+7 ----
    const int lane = tid & 63;
    const int wid  = tid >> 6;
    #pragma unroll
    for (int k = 0; k < 8; ++k) {
        int b = wid * 8 + k;
        if (b < N_BINS) {
            float4 v = *reinterpret_cast<const float4*>(&s_acc[b * BLOCK + 4 * lane]);
            float s = (v.x + v.y) + (v.z + v.w);
            s += __shfl_xor(s, 1);  s += __shfl_xor(s, 2);  s += __shfl_xor(s, 4);
            s += __shfl_xor(s, 8);  s += __shfl_xor(s, 16); s += __shfl_xor(s, 32);
            if (lane == 0) {
                long long fx = (long long)llrintf(s * 1048576.0f);  // 2^20 fixed point
                atomicAdd(&g_sum[b], (unsigned long long)fx);       // int: order-independent
            }
        }
    }
    __threadfence();
    __syncthreads();

    if (tid == 0)
        s_last = (atomicAdd(done, 1u) == gridDim.x - 1) ? 1u : 0u;
    __syncthreads();

    // ---- last block finalizes (wave 0, parallel coherent reads) ----
    if (s_last && wid == 0) {
        float g = 0.0f;
        if (lane < N_BINS) {
            __threadfence();
            long long v = (long long)atomicAdd(&g_sum[lane], 0ull);  // coherent read
            g = fabsf((float)((double)v * (1.0 / 1048576.0)));
        }
        g += __shfl_xor(g, 1);  g += __shfl_xor(g, 2);  g += __shfl_xor(g, 4);
        g += __shfl_xor(g, 8);  g += __shfl_xor(g, 16); g += __shfl_xor(g, 32);
        if (lane == 0) out[0] = g / (float)n;
    }
}

extern "C" void kernel_launch(void* const* d_in, const int* in_sizes, int n_in,
                              void* d_out, int out_size, void* d_ws, size_t ws_size,
                              hipStream_t stream) {
    const float* sm   = (const float*)d_in[0];
    const int* labels = (const int*)d_in[1];
    const int n = in_sizes[1];   // 4,000,000 rows

    unsigned long long* g_sum = (unsigned long long*)d_ws;
    unsigned int* done = (unsigned int*)(g_sum + N_BINS);

    hipMemsetAsync(d_ws, 0,
                   N_BINS * sizeof(unsigned long long) + sizeof(unsigned int),
                   stream);
    ece_hist<<<GRID, BLOCK, 0, stream>>>(sm, labels, n, g_sum, done,
                                         (float*)d_out);
}

// Round 7
// 380.662 us; speedup vs baseline: 1.0704x; 1.0704x over previous
//
#include <hip/hip_runtime.h>

#define N_BINS 30
#define BLOCK 256
#define GRID 2048
#define T_TOTAL (GRID * BLOCK)     // 524288 threads; 8 rows/thread max @ n=4M

// ECE = sum_b | sum_{i in bin b} (conf_i - acc_i) | / N  (counts cancel).
// Accumulator: per-thread private column in LDS (R6, race-free, conflict-free).
// This round: 8-row software pipeline -> 48 loads in flight per thread before
// any consumption (R6 was latency-serialized: 1 row chain in flight per wave).

struct Row { float2 a, b, c, d, e; };

__device__ __forceinline__ Row load_row(const float* __restrict__ p) {
    Row r;
    r.a = *reinterpret_cast<const float2*>(p + 0);
    r.b = *reinterpret_cast<const float2*>(p + 2);
    r.c = *reinterpret_cast<const float2*>(p + 4);
    r.d = *reinterpret_cast<const float2*>(p + 6);
    r.e = *reinterpret_cast<const float2*>(p + 8);
    return r;
}

__device__ __forceinline__ void proc_row(const Row& q, int lbl, bool valid,
                                         float* __restrict__ s_col) {
    float conf = q.a.x; int pred = 0;
    if (q.a.y > conf) { conf = q.a.y; pred = 1; }
    if (q.b.x > conf) { conf = q.b.x; pred = 2; }
    if (q.b.y > conf) { conf = q.b.y; pred = 3; }
    if (q.c.x > conf) { conf = q.c.x; pred = 4; }
    if (q.c.y > conf) { conf = q.c.y; pred = 5; }
    if (q.d.x > conf) { conf = q.d.x; pred = 6; }
    if (q.d.y > conf) { conf = q.d.y; pred = 7; }
    if (q.e.x > conf) { conf = q.e.x; pred = 8; }
    if (q.e.y > conf) { conf = q.e.y; pred = 9; }

    int bin = min(max((int)ceilf(conf * 30.0f) - 1, 0), N_BINS - 1);
    float d = conf - ((pred == lbl) ? 1.0f : 0.0f);
    d = valid ? d : 0.0f;                 // clamped duplicate rows contribute 0
    s_col[bin * BLOCK] += d;              // private slot: ds_read + add + ds_write
}

__global__ __launch_bounds__(BLOCK) void ece_hist(
        const float* __restrict__ sm,
        const int*   __restrict__ labels,
        int n,
        unsigned long long* __restrict__ g_sum,
        unsigned int* __restrict__ done,
        float* __restrict__ out) {
    __shared__ float s_acc[N_BINS * BLOCK];   // 30 KB: [bin][thread]
    __shared__ unsigned int s_last;

    const int tid = threadIdx.x;
    float* s_col = &s_acc[tid];

    #pragma unroll
    for (int b = 0; b < N_BINS; ++b) s_acc[b * BLOCK + tid] = 0.0f;
    // no barrier needed: each thread touches only its own column until flush

    const int gid = blockIdx.x * BLOCK + tid;
    const int nm1 = n - 1;

    // row indices (k*T_TOTAL stride keeps every wave's 64 lanes contiguous)
    const int r0 = gid;
    const int r1 = gid + 1 * T_TOTAL;
    const int r2 = gid + 2 * T_TOTAL;
    const int r3 = gid + 3 * T_TOTAL;
    const int r4 = gid + 4 * T_TOTAL;
    const int r5 = gid + 5 * T_TOTAL;
    const int r6 = gid + 6 * T_TOTAL;
    const int r7 = gid + 7 * T_TOTAL;

    const int c0 = min(r0, nm1), c1 = min(r1, nm1), c2 = min(r2, nm1),
              c3 = min(r3, nm1), c4 = min(r4, nm1), c5 = min(r5, nm1),
              c6 = min(r6, nm1), c7 = min(r7, nm1);

    // ---- issue ALL loads first: 48 independent VMEM ops in flight ----
    Row q0 = load_row(sm + (long long)c0 * 10);
    Row q1 = load_row(sm + (long long)c1 * 10);
    Row q2 = load_row(sm + (long long)c2 * 10);
    Row q3 = load_row(sm + (long long)c3 * 10);
    Row q4 = load_row(sm + (long long)c4 * 10);
    Row q5 = load_row(sm + (long long)c5 * 10);
    Row q6 = load_row(sm + (long long)c6 * 10);
    Row q7 = load_row(sm + (long long)c7 * 10);
    int l0 = labels[c0], l1 = labels[c1], l2 = labels[c2], l3 = labels[c3];
    int l4 = labels[c4], l5 = labels[c5], l6 = labels[c6], l7 = labels[c7];

    // ---- consume ----
    proc_row(q0, l0, r0 <= nm1, s_col);
    proc_row(q1, l1, r1 <= nm1, s_col);
    proc_row(q2, l2, r2 <= nm1, s_col);
    proc_row(q3, l3, r3 <= nm1, s_col);
    proc_row(q4, l4, r4 <= nm1, s_col);
    proc_row(q5, l5, r5 <= nm1, s_col);
    proc_row(q6, l6, r6 <= nm1, s_col);
    proc_row(q7, l7, r7 <= nm1, s_col);

    __syncthreads();

    // ---- block flush: wave w reduces bins 8w..8w+7 ----
    const int lane = tid & 63;
    const int wid  = tid >> 6;
    #pragma unroll
    for (int k = 0; k < 8; ++k) {
        int b = wid * 8 + k;
        if (b < N_BINS) {
            float4 v = *reinterpret_cast<const float4*>(&s_acc[b * BLOCK + 4 * lane]);
            float s = (v.x + v.y) + (v.z + v.w);
            s += __shfl_xor(s, 1);  s += __shfl_xor(s, 2);  s += __shfl_xor(s, 4);
            s += __shfl_xor(s, 8);  s += __shfl_xor(s, 16); s += __shfl_xor(s, 32);
            if (lane == 0) {
                long long fx = (long long)llrintf(s * 1048576.0f);  // 2^20 fixed point
                atomicAdd(&g_sum[b], (unsigned long long)fx);       // int: order-independent
            }
        }
    }
    __threadfence();
    __syncthreads();

    if (tid == 0)
        s_last = (atomicAdd(done, 1u) == gridDim.x - 1) ? 1u : 0u;
    __syncthreads();

    // ---- last block finalizes ----
    if (s_last && wid == 0) {
        float g = 0.0f;
        if (lane < N_BINS) {
            __threadfence();
            long long v = (long long)atomicAdd(&g_sum[lane], 0ull);  // coherent read
            g = fabsf((float)((double)v * (1.0 / 1048576.0)));
        }
        g += __shfl_xor(g, 1);  g += __shfl_xor(g, 2);  g += __shfl_xor(g, 4);
        g += __shfl_xor(g, 8);  g += __shfl_xor(g, 16); g += __shfl_xor(g, 32);
        if (lane == 0) out[0] = g / (float)n;
    }
}

extern "C" void kernel_launch(void* const* d_in, const int* in_sizes, int n_in,
                              void* d_out, int out_size, void* d_ws, size_t ws_size,
                              hipStream_t stream) {
    const float* sm   = (const float*)d_in[0];
    const int* labels = (const int*)d_in[1];
    const int n = in_sizes[1];   // 4,000,000 rows

    unsigned long long* g_sum = (unsigned long long*)d_ws;
    unsigned int* done = (unsigned int*)(g_sum + N_BINS);

    hipMemsetAsync(d_ws, 0,
                   N_BINS * sizeof(unsigned long long) + sizeof(unsigned int),
                   stream);
    ece_hist<<<GRID, BLOCK, 0, stream>>>(sm, labels, n, g_sum, done,
                                         (float*)d_out);
}

// Round 8
// 132.502 us; speedup vs baseline: 3.0750x; 2.8729x over previous
//
#include <hip/hip_runtime.h>

#define N_BINS 30
#define BLOCK 256
#define GRID 1024                 // 4 blocks/CU; 4096 waves; ~7.6 batches/wave
#define ROWS_PER_BATCH 128        // per wave per batch: 1280 floats = 320 float4

// ECE = sum_b | sum_{i in bin b} (conf_i - correct_i) | / N   (counts cancel).
// Copy-kernel-style loads: 5 lane-contiguous float4 per lane per batch (each
// VMEM instr = 4KB contiguous), LDS bounce (conflict-free write & b128 read),
// register double-buffer for prefetch depth 1. Per-wave i32 LDS histogram,
// <=2 LDS atomics per lane per 128-row batch. Integer everywhere -> exact.

__device__ __forceinline__ void row_stat(
        float v0, float v1, float v2, float v3, float v4,
        float v5, float v6, float v7, float v8, float v9,
        int lbl, int& bin, int& dfx) {
    float conf = v0; int pred = 0;
    if (v1 > conf) { conf = v1; pred = 1; }
    if (v2 > conf) { conf = v2; pred = 2; }
    if (v3 > conf) { conf = v3; pred = 3; }
    if (v4 > conf) { conf = v4; pred = 4; }
    if (v5 > conf) { conf = v5; pred = 5; }
    if (v6 > conf) { conf = v6; pred = 6; }
    if (v7 > conf) { conf = v7; pred = 7; }
    if (v8 > conf) { conf = v8; pred = 8; }
    if (v9 > conf) { conf = v9; pred = 9; }
    bin = min(max((int)ceilf(conf * 30.0f) - 1, 0), N_BINS - 1);
    float d = conf - ((pred == lbl) ? 1.0f : 0.0f);
    dfx = (int)lrintf(d * 1048576.0f);      // 2^20 fixed point, signed
}

__global__ __launch_bounds__(BLOCK) void ece_hist(
        const float* __restrict__ sm,
        const int*   __restrict__ labels,
        int n,
        unsigned long long* __restrict__ g_sum,
        unsigned int* __restrict__ done,
        float* __restrict__ out) {
    __shared__ float4 s_stage[4][320];     // 20 KB: per-wave 5120B stage
    __shared__ int    s_whist[4][32];      // per-wave i32 histogram (pad 30->32)
    __shared__ unsigned int s_last;

    const int tid  = threadIdx.x;
    const int lane = tid & 63;
    const int wid  = tid >> 6;

    if (lane < N_BINS) s_whist[wid][lane] = 0;   // wave-private: no barrier needed

    const int nb = n / ROWS_PER_BATCH;           // full batches
    const int nwaves = gridDim.x * 4;
    const int wgid = blockIdx.x * 4 + wid;
    const float4* sm4 = reinterpret_cast<const float4*>(sm);
    float4* stg = s_stage[wid];
    int* whist = s_whist[wid];

    int b = wgid;
    float4 a0, a1, a2, a3, a4; int2 la;
    if (b < nb) {
        const float4* p = sm4 + (size_t)320 * b;
        a0 = p[lane]; a1 = p[64 + lane]; a2 = p[128 + lane];
        a3 = p[192 + lane]; a4 = p[256 + lane];
        la = *reinterpret_cast<const int2*>(labels + (size_t)ROWS_PER_BATCH * b + 2 * lane);
    }

    while (b < nb) {
        const int bn = b + nwaves;
        // ---- stage current batch (waits vmcnt; conflict-free writes) ----
        stg[lane] = a0; stg[64 + lane] = a1; stg[128 + lane] = a2;
        stg[192 + lane] = a3; stg[256 + lane] = a4;
        const int2 lcur = la;

        // ---- prefetch next batch (in flight during compute below) ----
        if (bn < nb) {
            const float4* p = sm4 + (size_t)320 * bn;
            a0 = p[lane]; a1 = p[64 + lane]; a2 = p[128 + lane];
            a3 = p[192 + lane]; a4 = p[256 + lane];
            la = *reinterpret_cast<const int2*>(labels + (size_t)ROWS_PER_BATCH * bn + 2 * lane);
        }

        // ---- read my 2 rows: 5 x b128 at 80B stride (conflict-free) ----
        const float* base = reinterpret_cast<const float*>(stg) + 20 * lane;
        float4 f0 = *reinterpret_cast<const float4*>(base + 0);
        float4 f1 = *reinterpret_cast<const float4*>(base + 4);
        float4 f2 = *reinterpret_cast<const float4*>(base + 8);
        float4 f3 = *reinterpret_cast<const float4*>(base + 12);
        float4 f4 = *reinterpret_cast<const float4*>(base + 16);

        int binA, dfxA, binB, dfxB;
        row_stat(f0.x, f0.y, f0.z, f0.w, f1.x, f1.y, f1.z, f1.w, f2.x, f2.y,
                 lcur.x, binA, dfxA);
        row_stat(f2.z, f2.w, f3.x, f3.y, f3.z, f3.w, f4.x, f4.y, f4.z, f4.w,
                 lcur.y, binB, dfxB);

        if (binA == binB) {
            atomicAdd(&whist[binA], dfxA + dfxB);
        } else {
            atomicAdd(&whist[binA], dfxA);
            atomicAdd(&whist[binB], dfxB);
        }
        b = bn;
    }

    // ---- tail rows (n % 128), handled by block 0 wave 0 ----
    if (blockIdx.x == 0 && wid == 0) {
        for (int t = nb * ROWS_PER_BATCH + lane; t < n; t += 64) {
            const float* row = sm + (size_t)t * 10;
            float2 q0 = *reinterpret_cast<const float2*>(row + 0);
            float2 q1 = *reinterpret_cast<const float2*>(row + 2);
            float2 q2 = *reinterpret_cast<const float2*>(row + 4);
            float2 q3 = *reinterpret_cast<const float2*>(row + 6);
            float2 q4 = *reinterpret_cast<const float2*>(row + 8);
            int bin, dfx;
            row_stat(q0.x, q0.y, q1.x, q1.y, q2.x, q2.y, q3.x, q3.y, q4.x, q4.y,
                     labels[t], bin, dfx);
            atomicAdd(&whist[bin], dfx);
        }
    }
    __syncthreads();

    // ---- block flush: i64 sum of 4 wave-hists, one global atomic per bin ----
    if (tid < N_BINS) {
        long long s = (long long)s_whist[0][tid] + (long long)s_whist[1][tid]
                    + (long long)s_whist[2][tid] + (long long)s_whist[3][tid];
        if (s != 0)
            atomicAdd(&g_sum[tid], (unsigned long long)s);   // two's-complement: exact
    }
    __threadfence();
    __syncthreads();

    if (tid == 0)
        s_last = (atomicAdd(done, 1u) == gridDim.x - 1) ? 1u : 0u;
    __syncthreads();

    // ---- last block finalizes ----
    if (s_last && wid == 0) {
        float g = 0.0f;
        if (lane < N_BINS) {
            __threadfence();
            long long v = (long long)atomicAdd(&g_sum[lane], 0ull);  // coherent read
            g = fabsf((float)((double)v * (1.0 / 1048576.0)));
        }
        g += __shfl_xor(g, 1);  g += __shfl_xor(g, 2);  g += __shfl_xor(g, 4);
        g += __shfl_xor(g, 8);  g += __shfl_xor(g, 16); g += __shfl_xor(g, 32);
        if (lane == 0) out[0] = g / (float)n;
    }
}

extern "C" void kernel_launch(void* const* d_in, const int* in_sizes, int n_in,
                              void* d_out, int out_size, void* d_ws, size_t ws_size,
                              hipStream_t stream) {
    const float* sm   = (const float*)d_in[0];
    const int* labels = (const int*)d_in[1];
    const int n = in_sizes[1];   // 4,000,000 rows

    unsigned long long* g_sum = (unsigned long long*)d_ws;
    unsigned int* done = (unsigned int*)(g_sum + N_BINS);

    hipMemsetAsync(d_ws, 0,
                   N_BINS * sizeof(unsigned long long) + sizeof(unsigned int),
                   stream);
    ece_hist<<<GRID, BLOCK, 0, stream>>>(sm, labels, n, g_sum, done,
                                         (float*)d_out);
}